// Round 6
// baseline (216.243 us; speedup 1.0000x reference)
//
#include <hip/hip_runtime.h>
#include <hip/hip_fp16.h>
#include <cstdint>
#include <cstddef>

// ---------------------------------------------------------------------------
// SelfAttentionV2: out = softmax((x Wq + bq)(x Wk + bk)^T / 32) (x Wv + bv)
// N=4096, D=1024. fp32 in/out, fp16 MFMA internal.
// R6: R5 structure (2-wave 128x128 blocks, fused prep, XCD banding) with the
//     rowsum race fixed: S-GEMM writes per-(row,ntile) partial sums with
//     plain stores (no atomics, NO zero-init needed -> no aliasing race);
//     add_inv reduces the 32 partials per row.
// ---------------------------------------------------------------------------

#define NTOK 4096
#define DIM  1024

typedef _Float16 half8  __attribute__((ext_vector_type(8)));
typedef _Float16 half4v __attribute__((ext_vector_type(4)));
typedef float    floatx4 __attribute__((ext_vector_type(4)));

#define GLOBAL_AS __attribute__((address_space(1)))
#define LDS_AS    __attribute__((address_space(3)))

__device__ __forceinline__ void lds_load16(const _Float16* gsrc, _Float16* ldst) {
    __builtin_amdgcn_global_load_lds((GLOBAL_AS void*)gsrc, (LDS_AS void*)ldst, 16, 0, 0);
}

// ---------------------------------------------------------------------------
// 2-WAVE NT GEMM core: block tile 128(m) x 128(n), BK=64, swizzled LDS.
// 128 threads = 2 waves; wave w covers m-rows [w*64, w*64+64), full 128 n
// (4mi x 8ni of 16x16x32 MFMA).
// LDS row = 64 halfs = 128 B; physical 16B chunk pc of row r holds logical
// chunk pc ^ (r&7): fragment reads tile all 32 banks 2-way (free).
// ---------------------------------------------------------------------------
__device__ __forceinline__ void gemm_core2(const _Float16* __restrict__ A,
                                           const _Float16* __restrict__ B,
                                           int K, int lda, int ldb,
                                           int m0, int n0,
                                           _Float16* ldsA, _Float16* ldsB,
                                           floatx4 acc[4][8])
{
    const int t    = threadIdx.x;    // 0..127
    const int lane = t & 63;
    const int wid  = t >> 6;
    const int wm   = wid * 64;
    const int lrow = lane & 15;
    const int q    = lane >> 4;
    const int xk   = lrow & 7;

    const _Float16* asrc[8]; _Float16* adst[8];
    const _Float16* bsrc[8]; _Float16* bdst[8];
    #pragma unroll
    for (int i = 0; i < 8; ++i) {
        const int p = t + 128 * i, row = p >> 3;
        const int col = ((p & 7) ^ (row & 7)) * 8;
        asrc[i] = A + (size_t)(m0 + row) * lda + col;
        adst[i] = ldsA + p * 8;
        bsrc[i] = B + (size_t)(n0 + row) * ldb + col;
        bdst[i] = ldsB + p * 8;
    }

    const _Float16* fa = ldsA + (wm + lrow) * 64;
    const _Float16* fb = ldsB + lrow * 64;

    for (int k0 = 0; k0 < K; k0 += 64) {
        #pragma unroll
        for (int i = 0; i < 8; ++i) lds_load16(asrc[i] + k0, adst[i]);
        #pragma unroll
        for (int i = 0; i < 8; ++i) lds_load16(bsrc[i] + k0, bdst[i]);
        __syncthreads();

        #pragma unroll
        for (int s = 0; s < 2; ++s) {
            const int co = (((s * 4 + q) ^ xk) * 8);
            half8 af[4], bf[8];
            #pragma unroll
            for (int i = 0; i < 4; ++i) af[i] = *(const half8*)(fa + i * 1024 + co);
            #pragma unroll
            for (int i = 0; i < 8; ++i) bf[i] = *(const half8*)(fb + i * 1024 + co);
            #pragma unroll
            for (int ni = 0; ni < 8; ++ni)
                #pragma unroll
                for (int mi = 0; mi < 4; ++mi)
                    acc[mi][ni] = __builtin_amdgcn_mfma_f32_16x16x32_f16(
                        af[mi], bf[ni], acc[mi][ni], 0, 0, 0);
        }
        __syncthreads();
    }
}

// ---------------------------------------------------------------------------
// K0: fused prep. blocks [0,4096): x fp32->fp16; [4096,7168): W transpose+
// convert (3 matrices). NO rowsum zeroing (rowsum is store-only now).
// ---------------------------------------------------------------------------
__global__ __launch_bounds__(256) void prep_kernel(const float* __restrict__ x,
                                                   const float* __restrict__ W0,
                                                   const float* __restrict__ W1,
                                                   const float* __restrict__ W2,
                                                   _Float16* __restrict__ xh,
                                                   _Float16* __restrict__ Wt)
{
    __shared__ float tile[32][33];
    const int b = blockIdx.x;
    const int t = threadIdx.x;

    if (b < 4096) {
        size_t i = ((size_t)b * 256 + t) * 4;
        float4 v = *(const float4*)(x + i);
        half4v h;
        h[0] = (_Float16)v.x; h[1] = (_Float16)v.y;
        h[2] = (_Float16)v.z; h[3] = (_Float16)v.w;
        *(half4v*)(xh + i) = h;
    } else {
        const int bb = b - 4096;
        const int z  = bb >> 10;
        const int r  = bb & 1023;
        const int nb = (r & 31) * 32, kb = (r >> 5) * 32;
        const float* W = (z == 0) ? W0 : (z == 1) ? W1 : W2;
        _Float16* out = Wt + (size_t)z * DIM * DIM;
        const int tx = t & 31, ty = t >> 5;   // (32, 8)
        #pragma unroll
        for (int i = 0; i < 32; i += 8)
            tile[ty + i][tx] = W[(size_t)(kb + ty + i) * DIM + nb + tx];
        __syncthreads();
        #pragma unroll
        for (int i = 0; i < 32; i += 8)
            out[(size_t)(nb + ty + i) * DIM + kb + tx] = (_Float16)tile[tx][ty + i];
    }
}

// ---------------------------------------------------------------------------
// K1: fused QKV. flat grid 768: f>>8 selects matrix (0:q 1:k 2:v^T).
// q,k: [4096][1024] = 32mt x 8nt; v^T: [1024][4096] = 8mt x 32nt.
// xcd = g&7 owns an m-band (L2 locality).
// ---------------------------------------------------------------------------
__global__ __launch_bounds__(128, 2) void qkv_kernel(const _Float16* __restrict__ xh,
                                                     const _Float16* __restrict__ Wt,
                                                     const float* __restrict__ bq,
                                                     const float* __restrict__ bk,
                                                     const float* __restrict__ bv,
                                                     _Float16* __restrict__ qh,
                                                     _Float16* __restrict__ kh,
                                                     _Float16* __restrict__ vt)
{
    __shared__ _Float16 ldsA[128 * 64];
    __shared__ _Float16 ldsB[128 * 64];

    const int f   = blockIdx.x;
    const int z   = f >> 8;          // 0,1,2
    const int g   = f & 255;
    const int xcd = g & 7;
    const int j   = g >> 3;          // 0..31

    const _Float16* A; const _Float16* B;
    const float* bias; _Float16* out;
    int m0, n0, ldc; bool bias_by_row;

    if (z < 2) {
        const int mt = xcd * 4 + (j & 3);   // 32 m-tiles
        const int nt = j >> 2;              // 8 n-tiles
        m0 = mt * 128; n0 = nt * 128; ldc = DIM; bias_by_row = false;
        A = xh;
        B = (z == 0) ? Wt : Wt + DIM * DIM;
        bias = (z == 0) ? bq : bk;
        out  = (z == 0) ? qh : kh;
    } else {
        m0 = xcd * 128; n0 = j * 128; ldc = NTOK; bias_by_row = true;
        A = Wt + 2 * DIM * DIM; B = xh; bias = bv; out = vt;
    }

    floatx4 acc[4][8];
    #pragma unroll
    for (int mi = 0; mi < 4; ++mi)
        #pragma unroll
        for (int ni = 0; ni < 8; ++ni)
            #pragma unroll
            for (int r = 0; r < 4; ++r) acc[mi][ni][r] = 0.0f;

    gemm_core2(A, B, DIM, DIM, DIM, m0, n0, ldsA, ldsB, acc);

    const int lane = threadIdx.x & 63;
    const int wm   = (threadIdx.x >> 6) * 64;
    const int lrow = lane & 15;
    const int q    = lane >> 4;
    #pragma unroll
    for (int mi = 0; mi < 4; ++mi) {
        #pragma unroll
        for (int ni = 0; ni < 8; ++ni) {
            const int gm = m0 + wm + mi * 16 + q * 4;
            const int gn = n0 + ni * 16 + lrow;
            const float bcol = bias_by_row ? 0.0f : bias[gn];
            #pragma unroll
            for (int r = 0; r < 4; ++r) {
                float bb = bias_by_row ? bias[gm + r] : bcol;
                out[(size_t)(gm + r) * ldc + gn] = (_Float16)(acc[mi][ni][r] + bb);
            }
        }
    }
}

// ---------------------------------------------------------------------------
// K2: S-GEMM with fused exp + PARTIAL rowsums. P = exp(q k^T/32 - 8) fp16;
// rowsum_part[row*32 + nt] = sum over this block's 128 columns (plain store,
// each slot written by exactly one block -> no init, no atomics).
// grid 1024 (32mt x 32nt), XCD-banded.
// ---------------------------------------------------------------------------
__global__ __launch_bounds__(128, 2) void gemm_qk_exp(const _Float16* __restrict__ qh,
                                                      const _Float16* __restrict__ kh,
                                                      _Float16* __restrict__ P,
                                                      float* __restrict__ rowsum_part)
{
    __shared__ _Float16 ldsA[128 * 64];
    __shared__ _Float16 ldsB[128 * 64];

    const int f   = blockIdx.x;      // 0..1023
    const int xcd = f & 7;
    const int j   = f >> 3;          // 0..127
    const int mt  = xcd * 4 + (j & 3);   // 32 m-tiles
    const int nt  = j >> 2;              // 32 n-tiles
    const int m0  = mt * 128;
    const int n0  = nt * 128;

    floatx4 acc[4][8];
    #pragma unroll
    for (int mi = 0; mi < 4; ++mi)
        #pragma unroll
        for (int ni = 0; ni < 8; ++ni)
            #pragma unroll
            for (int r = 0; r < 4; ++r) acc[mi][ni][r] = 0.0f;

    gemm_core2(qh, kh, DIM, DIM, DIM, m0, n0, ldsA, ldsB, acc);

    const int lane = threadIdx.x & 63;
    const int wm   = (threadIdx.x >> 6) * 64;
    const int lrow = lane & 15;
    const int q    = lane >> 4;

    #pragma unroll
    for (int mi = 0; mi < 4; ++mi) {
        #pragma unroll
        for (int r = 0; r < 4; ++r) {
            const int gm = m0 + wm + mi * 16 + q * 4 + r;
            float rs = 0.0f;
            #pragma unroll
            for (int ni = 0; ni < 8; ++ni) {
                const int gn = n0 + ni * 16 + lrow;
                float e = __expf(acc[mi][ni][r] * 0.03125f - 8.0f);
                P[(size_t)gm * NTOK + gn] = (_Float16)e;
                rs += e;
            }
            rs += __shfl_xor(rs, 1, 64);
            rs += __shfl_xor(rs, 2, 64);
            rs += __shfl_xor(rs, 4, 64);
            rs += __shfl_xor(rs, 8, 64);
            if (lrow == 0) rowsum_part[(size_t)gm * 32 + nt] = rs;
        }
    }
}

// ---------------------------------------------------------------------------
// K3: PV (split-K=4). grid (256,1,4): z=0 -> out fp32 raw; z=1..3 -> fp16
// partials. 32mt x 8nt per z, XCD-banded.
// ---------------------------------------------------------------------------
__global__ __launch_bounds__(128, 2) void gemm_pv(const _Float16* __restrict__ P,
                                                  const _Float16* __restrict__ vt,
                                                  float* __restrict__ out,
                                                  _Float16* __restrict__ P1,
                                                  _Float16* __restrict__ P2,
                                                  _Float16* __restrict__ P3)
{
    __shared__ _Float16 ldsA[128 * 64];
    __shared__ _Float16 ldsB[128 * 64];

    const int z   = blockIdx.z;
    const int g   = blockIdx.x;      // 0..255
    const int xcd = g & 7;
    const int j   = g >> 3;          // 0..31
    const int mt  = xcd * 4 + (j & 3);   // 32 m-tiles
    const int nt  = j >> 2;              // 8 n-tiles
    const int m0  = mt * 128;
    const int n0  = nt * 128;
    const int kstart = z * (NTOK / 4);

    floatx4 acc[4][8];
    #pragma unroll
    for (int mi = 0; mi < 4; ++mi)
        #pragma unroll
        for (int ni = 0; ni < 8; ++ni)
            #pragma unroll
            for (int r = 0; r < 4; ++r) acc[mi][ni][r] = 0.0f;

    gemm_core2(P + kstart, vt + kstart, NTOK / 4, NTOK, NTOK, m0, n0,
               ldsA, ldsB, acc);

    const int lane = threadIdx.x & 63;
    const int wm   = (threadIdx.x >> 6) * 64;
    const int lrow = lane & 15;
    const int q    = lane >> 4;

    _Float16* ph = (z == 1) ? P1 : (z == 2) ? P2 : P3;
    #pragma unroll
    for (int mi = 0; mi < 4; ++mi) {
        #pragma unroll
        for (int ni = 0; ni < 8; ++ni) {
            const int gm = m0 + wm + mi * 16 + q * 4;
            const int gn = n0 + ni * 16 + lrow;
            #pragma unroll
            for (int r = 0; r < 4; ++r) {
                if (z == 0) out[(size_t)(gm + r) * DIM + gn] = acc[mi][ni][r];
                else        ph[(size_t)(gm + r) * DIM + gn] = (_Float16)acc[mi][ni][r];
            }
        }
    }
}

// ---------------------------------------------------------------------------
// K4: out = (out + P1 + P2 + P3) / rowsum[row]; rowsum = sum of 32 partials.
// One block (256 thr) per row.
// ---------------------------------------------------------------------------
__global__ __launch_bounds__(256) void add_inv_kernel(float* __restrict__ out,
                                                      const _Float16* __restrict__ P1,
                                                      const _Float16* __restrict__ P2,
                                                      const _Float16* __restrict__ P3,
                                                      const float* __restrict__ rowsum_part)
{
    const int row = blockIdx.x;
    const int t   = threadIdx.x;
    __shared__ float s_inv;

    if (t < 64) {
        float v = (t < 32) ? rowsum_part[(size_t)row * 32 + t] : 0.0f;
        v += __shfl_xor(v, 16, 64);
        v += __shfl_xor(v, 8, 64);
        v += __shfl_xor(v, 4, 64);
        v += __shfl_xor(v, 2, 64);
        v += __shfl_xor(v, 1, 64);
        if (t == 0) s_inv = 1.0f / v;
    }
    __syncthreads();
    const float inv = s_inv;

    size_t i = (size_t)row * DIM + t * 4;
    float4 a = *(const float4*)(out + i);
    half4v b1 = *(const half4v*)(P1 + i);
    half4v b2 = *(const half4v*)(P2 + i);
    half4v b3 = *(const half4v*)(P3 + i);
    a.x = (a.x + (float)b1[0] + (float)b2[0] + (float)b3[0]) * inv;
    a.y = (a.y + (float)b1[1] + (float)b2[1] + (float)b3[1]) * inv;
    a.z = (a.z + (float)b1[2] + (float)b2[2] + (float)b3[2]) * inv;
    a.w = (a.w + (float)b1[3] + (float)b2[3] + (float)b3[3]) * inv;
    *(float4*)(out + i) = a;
}

// ---------------------------------------------------------------------------
// launch
// ---------------------------------------------------------------------------
extern "C" void kernel_launch(void* const* d_in, const int* in_sizes, int n_in,
                              void* d_out, int out_size, void* d_ws, size_t ws_size,
                              hipStream_t stream)
{
    const float* x  = (const float*)d_in[0];
    const float* Wq = (const float*)d_in[1];
    const float* Wk = (const float*)d_in[2];
    const float* Wv = (const float*)d_in[3];
    const float* bq = (const float*)d_in[4];
    const float* bk = (const float*)d_in[5];
    const float* bv = (const float*)d_in[6];
    float* out = (float*)d_out;

    char* ws = (char*)d_ws;
    // layout (70 MB peak, regions reused across dead phases):
    //   0..8    xh        (dead after QKV)
    //   8..14   Wt        (dead after QKV)
    //  14..22   qh        (dead after S-GEMM)
    //  22..30   kh        (dead after S-GEMM)
    //  30..38   vt        (alive through PV)
    //  38..70   S = P     (alive through PV)
    //  reuse: rowsum_part @0 (512 KB, STORED during S-GEMM; xh dead by then,
    //         P1 starts at 2 MB so no overlap; read in add_inv)
    //         P1/P2/P3 fp16 partials @2/11/20 MB (written during PV;
    //         xh/Wt/qh/kh dead)
    _Float16* xh = (_Float16*)(ws);
    _Float16* Wt = (_Float16*)(ws + (8ull  << 20));
    _Float16* qh = (_Float16*)(ws + (14ull << 20));
    _Float16* kh = (_Float16*)(ws + (22ull << 20));
    _Float16* vt = (_Float16*)(ws + (30ull << 20));
    _Float16* S  = (_Float16*)(ws + (38ull << 20));
    float* rowsum_part = (float*)(ws);
    _Float16* P1  = (_Float16*)(ws + (2ull  << 20));
    _Float16* P2  = (_Float16*)(ws + (11ull << 20));
    _Float16* P3  = (_Float16*)(ws + (20ull << 20));

    prep_kernel<<<dim3(7168), 256, 0, stream>>>(x, Wq, Wk, Wv, xh, Wt);
    qkv_kernel<<<dim3(768), 128, 0, stream>>>(xh, Wt, bq, bk, bv, qh, kh, vt);
    gemm_qk_exp<<<dim3(1024), 128, 0, stream>>>(qh, kh, S, rowsum_part);
    gemm_pv<<<dim3(256, 1, 4), 128, 0, stream>>>(S, vt, out, P1, P2, P3);
    add_inv_kernel<<<dim3(NTOK), 256, 0, stream>>>(out, P1, P2, P3, rowsum_part);
}